// Round 1
// baseline (721.425 us; speedup 1.0000x reference)
//
#include <hip/hip_runtime.h>

#define N_NODES 50000
#define N_EDGES 800000
#define DIM 256
#define ACT 64
#define BM 32
#define BK 32

// ---------------- degree / CSR build ----------------

__global__ void k_deg_init(int* degi) {
    int i = blockIdx.x * blockDim.x + threadIdx.x;
    if (i < N_NODES) degi[i] = 1;   // self-loop
}

__global__ void k_deg_count(const int* __restrict__ ei, int* degi) {
    int e = blockIdx.x * blockDim.x + threadIdx.x;
    if (e < N_EDGES) atomicAdd(&degi[ei[N_EDGES + e]], 1);  // dst row
}

__global__ __launch_bounds__(1024) void k_scan(const int* __restrict__ degi,
                                               int* rowstart, int* fillpos,
                                               float* dinv) {
    const int T = 1024;
    const int CH = (N_NODES + T - 1) / T;  // 49
    int t = threadIdx.x;
    int s0 = t * CH;
    int s1 = s0 + CH; if (s1 > N_NODES) s1 = N_NODES;
    int s = 0;
    for (int i = s0; i < s1; ++i) s += degi[i];
    __shared__ int part[T];
    part[t] = s;
    __syncthreads();
    for (int off = 1; off < T; off <<= 1) {
        int v = (t >= off) ? part[t - off] : 0;
        __syncthreads();
        part[t] += v;
        __syncthreads();
    }
    int base = part[t] - s;  // exclusive prefix
    for (int i = s0; i < s1; ++i) {
        rowstart[i] = base;
        fillpos[i] = base;
        int d = degi[i];
        base += d;
        dinv[i] = rsqrtf((float)d);
    }
    if (t == T - 1) rowstart[N_NODES] = part[T - 1];
}

__global__ void k_fill_self(const float* __restrict__ dinv, int* fillpos,
                            int* csr_src, float* csr_norm) {
    int i = blockIdx.x * blockDim.x + threadIdx.x;
    if (i < N_NODES) {
        int p = atomicAdd(&fillpos[i], 1);
        csr_src[p] = i;
        float d = dinv[i];
        csr_norm[p] = d * d;
    }
}

__global__ void k_fill_edge(const int* __restrict__ ei,
                            const float* __restrict__ dinv, int* fillpos,
                            int* csr_src, float* csr_norm) {
    int e = blockIdx.x * blockDim.x + threadIdx.x;
    if (e < N_EDGES) {
        int s = ei[e];
        int d = ei[N_EDGES + e];
        int p = atomicAdd(&fillpos[d], 1);
        csr_src[p] = s;
        csr_norm[p] = dinv[s] * dinv[d];
    }
}

// ---------------- fp32 GEMM: C[M,256] = A[M,256] @ B[256,256] ----------------

__global__ __launch_bounds__(256) void k_gemm(const float* __restrict__ A,
                                              const float* __restrict__ B,
                                              float* __restrict__ C) {
    __shared__ float As[BK][BM + 4];   // transposed [k][m], stride 36 floats (144B, 16B-mult)
    __shared__ float Bs[BK][DIM];
    int tid = threadIdx.x;
    int m0 = blockIdx.x * BM;
    int tx = tid & 63;        // col group: cols tx*4..tx*4+3
    int ty = tid >> 6;        // 0..3   rows ty*8..ty*8+7
    float4 acc[8];
#pragma unroll
    for (int j = 0; j < 8; ++j) acc[j] = make_float4(0.f, 0.f, 0.f, 0.f);

    int ka = tid & 31;
    int ma = (tid >> 5) << 2;

    for (int kt = 0; kt < DIM / BK; ++kt) {
        int k0 = kt * BK;
        // stage A transposed (4 scalars per thread)
#pragma unroll
        for (int i = 0; i < 4; ++i) {
            int r = m0 + ma + i;
            if (r > N_NODES - 1) r = N_NODES - 1;
            As[ka][ma + i] = A[r * DIM + k0 + ka];
        }
        // stage B: contiguous 32KB block
        const float4* Bsrc = (const float4*)(B + k0 * DIM);
        float4* Bd = (float4*)(&Bs[0][0]);
#pragma unroll
        for (int i = 0; i < 8; ++i) Bd[tid + i * 256] = Bsrc[tid + i * 256];
        __syncthreads();

#pragma unroll
        for (int k = 0; k < BK; ++k) {
            float4 b = *(const float4*)&Bs[k][tx << 2];
            float4 a0 = *(const float4*)&As[k][ty << 3];
            float4 a1 = *(const float4*)&As[k][(ty << 3) + 4];
            float av[8] = {a0.x, a0.y, a0.z, a0.w, a1.x, a1.y, a1.z, a1.w};
#pragma unroll
            for (int j = 0; j < 8; ++j) {
                acc[j].x = fmaf(av[j], b.x, acc[j].x);
                acc[j].y = fmaf(av[j], b.y, acc[j].y);
                acc[j].z = fmaf(av[j], b.z, acc[j].z);
                acc[j].w = fmaf(av[j], b.w, acc[j].w);
            }
        }
        __syncthreads();
    }
#pragma unroll
    for (int j = 0; j < 8; ++j) {
        int r = m0 + (ty << 3) + j;
        if (r < N_NODES) *(float4*)&C[r * DIM + (tx << 2)] = acc[j];
    }
}

// ---------------- aggregation: one wave per node, fused bias+ReLU ----------------

__global__ __launch_bounds__(256) void k_agg(const float* __restrict__ H,
                                             const int* __restrict__ rowstart,
                                             const int* __restrict__ csr_src,
                                             const float* __restrict__ csr_norm,
                                             const float* __restrict__ bias,
                                             float* __restrict__ X) {
    int wid = (blockIdx.x * blockDim.x + threadIdx.x) >> 6;  // node id
    int lane = threadIdx.x & 63;
    if (wid >= N_NODES) return;
    int beg = rowstart[wid];
    int end = rowstart[wid + 1];
    float4 acc = make_float4(0.f, 0.f, 0.f, 0.f);
    for (int e = beg; e < end; ++e) {
        int s = csr_src[e];
        float nm = csr_norm[e];
        float4 v = *(const float4*)&H[s * DIM + (lane << 2)];
        acc.x = fmaf(nm, v.x, acc.x);
        acc.y = fmaf(nm, v.y, acc.y);
        acc.z = fmaf(nm, v.z, acc.z);
        acc.w = fmaf(nm, v.w, acc.w);
    }
    float4 bb = *(const float4*)&bias[lane << 2];
    float4 o;
    o.x = fmaxf(acc.x + bb.x, 0.f);
    o.y = fmaxf(acc.y + bb.y, 0.f);
    o.z = fmaxf(acc.z + bb.z, 0.f);
    o.w = fmaxf(acc.w + bb.w, 0.f);
    *(float4*)&X[wid * DIM + (lane << 2)] = o;
}

// ---------------- column sum for mean-pool ----------------

__global__ __launch_bounds__(256) void k_colsum(const float* __restrict__ X,
                                                float* gsum) {
    int t = threadIdx.x;
    int b = blockIdx.x;
    const int RPB = (N_NODES + 255) / 256;  // 196
    int r0 = b * RPB;
    int r1 = r0 + RPB; if (r1 > N_NODES) r1 = N_NODES;
    float acc = 0.f;
    for (int r = r0; r < r1; ++r) acc += X[r * DIM + t];
    atomicAdd(&gsum[t], acc);
}

// ---------------- FC head (single block) ----------------

__global__ __launch_bounds__(256) void k_fc(const float* __restrict__ gsum,
                                            const float* __restrict__ fcW1,
                                            const float* __restrict__ fcb1,
                                            const float* __restrict__ fcW2,
                                            const float* __restrict__ fcb2,
                                            const float* __restrict__ fcW3,
                                            const float* __restrict__ fcb3,
                                            float* __restrict__ out) {
    __shared__ float g[DIM];
    __shared__ float h[DIM];
    int t = threadIdx.x;
    g[t] = fmaxf(gsum[t] * (1.0f / (float)N_NODES), 0.f);
    __syncthreads();
    float acc = fcb1[t];
    for (int k = 0; k < DIM; ++k) acc = fmaf(g[k], fcW1[k * DIM + t], acc);
    h[t] = fmaxf(acc, 0.f);
    __syncthreads();
    acc = fcb2[t];
    for (int k = 0; k < DIM; ++k) acc = fmaf(h[k], fcW2[k * DIM + t], acc);
    __syncthreads();
    g[t] = fmaxf(acc, 0.f);
    __syncthreads();
    if (t < ACT) {
        float o = fcb3[t];
        for (int k = 0; k < DIM; ++k) o = fmaf(g[k], fcW3[k * ACT + t], o);
        out[t] = o;
    }
}

// ---------------- launch ----------------

extern "C" void kernel_launch(void* const* d_in, const int* in_sizes, int n_in,
                              void* d_out, int out_size, void* d_ws, size_t ws_size,
                              hipStream_t stream) {
    const float* x    = (const float*)d_in[0];
    const int*   ei   = (const int*)d_in[1];
    const float* W1   = (const float*)d_in[2];
    const float* b1   = (const float*)d_in[3];
    const float* W2   = (const float*)d_in[4];
    const float* b2   = (const float*)d_in[5];
    const float* fcW1 = (const float*)d_in[6];
    const float* fcb1 = (const float*)d_in[7];
    const float* fcW2 = (const float*)d_in[8];
    const float* fcb2 = (const float*)d_in[9];
    const float* fcW3 = (const float*)d_in[10];
    const float* fcb3 = (const float*)d_in[11];
    float* out = (float*)d_out;

    char* w = (char*)d_ws;
    size_t o = 0;
#define CARVE(name, type, count) \
    type* name = (type*)(w + o); \
    o += (((size_t)(count) * sizeof(type)) + 255) & ~(size_t)255;
    CARVE(degi, int, N_NODES)
    CARVE(rowstart, int, N_NODES + 1)
    CARVE(fillpos, int, N_NODES)
    CARVE(dinv, float, N_NODES)
    CARVE(csr_src, int, N_NODES + N_EDGES)
    CARVE(csr_norm, float, N_NODES + N_EDGES)
    CARVE(gsum, float, DIM)
    CARVE(Hbuf, float, (size_t)N_NODES * DIM)
    CARVE(Xbuf, float, (size_t)N_NODES * DIM)
#undef CARVE

    hipMemsetAsync(gsum, 0, DIM * sizeof(float), stream);

    k_deg_init<<<(N_NODES + 255) / 256, 256, 0, stream>>>(degi);
    k_deg_count<<<(N_EDGES + 255) / 256, 256, 0, stream>>>(ei, degi);
    k_scan<<<1, 1024, 0, stream>>>(degi, rowstart, fillpos, dinv);
    k_fill_self<<<(N_NODES + 255) / 256, 256, 0, stream>>>(dinv, fillpos, csr_src, csr_norm);
    k_fill_edge<<<(N_EDGES + 255) / 256, 256, 0, stream>>>(ei, dinv, fillpos, csr_src, csr_norm);

    int gemm_grid = (N_NODES + BM - 1) / BM;
    k_gemm<<<gemm_grid, 256, 0, stream>>>(x, W1, Hbuf);
    k_agg<<<(N_NODES + 3) / 4, 256, 0, stream>>>(Hbuf, rowstart, csr_src, csr_norm, b1, Xbuf);
    k_gemm<<<gemm_grid, 256, 0, stream>>>(Xbuf, W2, Hbuf);
    k_agg<<<(N_NODES + 3) / 4, 256, 0, stream>>>(Hbuf, rowstart, csr_src, csr_norm, b2, Xbuf);

    k_colsum<<<256, 256, 0, stream>>>(Xbuf, gsum);
    k_fc<<<1, 256, 0, stream>>>(gsum, fcW1, fcb1, fcW2, fcb2, fcW3, fcb3, out);
}

// Round 2
// 588.285 us; speedup vs baseline: 1.2263x; 1.2263x over previous
//
#include <hip/hip_runtime.h>

#define N_NODES 50000
#define N_EDGES 800000
#define DIM 256
#define ACT 64
#define BM 32
#define BK 32
#define SCAN_B 256
#define SCAN_NB ((N_NODES + SCAN_B - 1) / SCAN_B)   // 196

// ---------------- degree ----------------

__global__ void k_deg_init(int* degi) {
    int i = blockIdx.x * blockDim.x + threadIdx.x;
    if (i < N_NODES) degi[i] = 1;   // self-loop
}

__global__ void k_deg_count(const int* __restrict__ ei, int* degi) {
    int e = blockIdx.x * blockDim.x + threadIdx.x;
    if (e < N_EDGES) atomicAdd(&degi[ei[N_EDGES + e]], 1);  // dst row
}

// ---------------- hierarchical exclusive scan of degrees ----------------

// stage 1: per-block local exclusive scan (256 elems) + block total
__global__ __launch_bounds__(SCAN_B) void k_scan_local(const int* __restrict__ degi,
                                                       int* lexc, int* btot) {
    __shared__ int sm[SCAN_B];
    int t = threadIdx.x;
    int i = blockIdx.x * SCAN_B + t;
    int v = (i < N_NODES) ? degi[i] : 0;
    sm[t] = v;
    __syncthreads();
#pragma unroll
    for (int off = 1; off < SCAN_B; off <<= 1) {
        int u = (t >= off) ? sm[t - off] : 0;
        __syncthreads();
        sm[t] += u;
        __syncthreads();
    }
    if (i < N_NODES) lexc[i] = sm[t] - v;          // exclusive
    if (t == SCAN_B - 1) btot[blockIdx.x] = sm[t]; // inclusive total
}

// stage 2: scan the 196 block totals (one block)
__global__ __launch_bounds__(SCAN_B) void k_scan_tops(const int* __restrict__ btot,
                                                      int* bbase, int* rowstart) {
    __shared__ int sm[SCAN_B];
    int t = threadIdx.x;
    int v = (t < SCAN_NB) ? btot[t] : 0;
    sm[t] = v;
    __syncthreads();
#pragma unroll
    for (int off = 1; off < SCAN_B; off <<= 1) {
        int u = (t >= off) ? sm[t - off] : 0;
        __syncthreads();
        sm[t] += u;
        __syncthreads();
    }
    if (t < SCAN_NB) bbase[t] = sm[t] - v;
    if (t == SCAN_NB - 1) rowstart[N_NODES] = sm[t];  // grand total = N_NODES+N_EDGES
}

// stage 3: write rowstart/dinv, fill self-loop entry, init fillpos past it
__global__ __launch_bounds__(SCAN_B) void k_scan_apply(const int* __restrict__ degi,
                                                       const int* __restrict__ lexc,
                                                       const int* __restrict__ bbase,
                                                       int* rowstart, int* fillpos,
                                                       float* dinv,
                                                       int* csr_src, float* csr_norm) {
    int i = blockIdx.x * SCAN_B + threadIdx.x;
    if (i >= N_NODES) return;
    int rs = bbase[blockIdx.x] + lexc[i];
    rowstart[i] = rs;
    int d = degi[i];
    float di = rsqrtf((float)d);
    dinv[i] = di;
    // self-loop entry goes first in the row
    csr_src[rs] = i;
    csr_norm[rs] = di * di;
    fillpos[i] = rs + 1;
}

__global__ void k_fill_edge(const int* __restrict__ ei,
                            const float* __restrict__ dinv, int* fillpos,
                            int* csr_src, float* csr_norm) {
    int e = blockIdx.x * blockDim.x + threadIdx.x;
    if (e < N_EDGES) {
        int s = ei[e];
        int d = ei[N_EDGES + e];
        int p = atomicAdd(&fillpos[d], 1);
        csr_src[p] = s;
        csr_norm[p] = dinv[s] * dinv[d];
    }
}

// ---------------- fp32 GEMM: C[M,256] = A[M,256] @ B[256,256] ----------------

__global__ __launch_bounds__(256) void k_gemm(const float* __restrict__ A,
                                              const float* __restrict__ B,
                                              float* __restrict__ C) {
    __shared__ float As[BK][BM + 4];   // transposed [k][m]
    __shared__ float Bs[BK][DIM];
    int tid = threadIdx.x;
    int m0 = blockIdx.x * BM;
    int tx = tid & 63;        // col group: cols tx*4..tx*4+3
    int ty = tid >> 6;        // 0..3   rows ty*8..ty*8+7
    float4 acc[8];
#pragma unroll
    for (int j = 0; j < 8; ++j) acc[j] = make_float4(0.f, 0.f, 0.f, 0.f);

    int ka = tid & 31;
    int ma = (tid >> 5) << 2;

    for (int kt = 0; kt < DIM / BK; ++kt) {
        int k0 = kt * BK;
#pragma unroll
        for (int i = 0; i < 4; ++i) {
            int r = m0 + ma + i;
            if (r > N_NODES - 1) r = N_NODES - 1;
            As[ka][ma + i] = A[r * DIM + k0 + ka];
        }
        const float4* Bsrc = (const float4*)(B + k0 * DIM);
        float4* Bd = (float4*)(&Bs[0][0]);
#pragma unroll
        for (int i = 0; i < 8; ++i) Bd[tid + i * 256] = Bsrc[tid + i * 256];
        __syncthreads();

#pragma unroll
        for (int k = 0; k < BK; ++k) {
            float4 b = *(const float4*)&Bs[k][tx << 2];
            float4 a0 = *(const float4*)&As[k][ty << 3];
            float4 a1 = *(const float4*)&As[k][(ty << 3) + 4];
            float av[8] = {a0.x, a0.y, a0.z, a0.w, a1.x, a1.y, a1.z, a1.w};
#pragma unroll
            for (int j = 0; j < 8; ++j) {
                acc[j].x = fmaf(av[j], b.x, acc[j].x);
                acc[j].y = fmaf(av[j], b.y, acc[j].y);
                acc[j].z = fmaf(av[j], b.z, acc[j].z);
                acc[j].w = fmaf(av[j], b.w, acc[j].w);
            }
        }
        __syncthreads();
    }
#pragma unroll
    for (int j = 0; j < 8; ++j) {
        int r = m0 + (ty << 3) + j;
        if (r < N_NODES) *(float4*)&C[r * DIM + (tx << 2)] = acc[j];
    }
}

// ---------------- aggregation: one wave per node, fused bias+ReLU ----------------

__global__ __launch_bounds__(256) void k_agg(const float* __restrict__ H,
                                             const int* __restrict__ rowstart,
                                             const int* __restrict__ csr_src,
                                             const float* __restrict__ csr_norm,
                                             const float* __restrict__ bias,
                                             float* __restrict__ X) {
    int wid = (blockIdx.x * blockDim.x + threadIdx.x) >> 6;  // node id
    int lane = threadIdx.x & 63;
    if (wid >= N_NODES) return;
    int beg = rowstart[wid];
    int end = rowstart[wid + 1];
    float4 acc = make_float4(0.f, 0.f, 0.f, 0.f);
    for (int e = beg; e < end; ++e) {
        int s = csr_src[e];
        float nm = csr_norm[e];
        float4 v = *(const float4*)&H[s * DIM + (lane << 2)];
        acc.x = fmaf(nm, v.x, acc.x);
        acc.y = fmaf(nm, v.y, acc.y);
        acc.z = fmaf(nm, v.z, acc.z);
        acc.w = fmaf(nm, v.w, acc.w);
    }
    float4 bb = *(const float4*)&bias[lane << 2];
    float4 o;
    o.x = fmaxf(acc.x + bb.x, 0.f);
    o.y = fmaxf(acc.y + bb.y, 0.f);
    o.z = fmaxf(acc.z + bb.z, 0.f);
    o.w = fmaxf(acc.w + bb.w, 0.f);
    *(float4*)&X[wid * DIM + (lane << 2)] = o;
}

// ---------------- column sum for mean-pool ----------------

__global__ __launch_bounds__(256) void k_colsum(const float* __restrict__ X,
                                                float* gsum) {
    int t = threadIdx.x;
    int b = blockIdx.x;
    const int RPB = (N_NODES + 255) / 256;  // 196
    int r0 = b * RPB;
    int r1 = r0 + RPB; if (r1 > N_NODES) r1 = N_NODES;
    float acc = 0.f;
    for (int r = r0; r < r1; ++r) acc += X[r * DIM + t];
    atomicAdd(&gsum[t], acc);
}

// ---------------- FC head (single block) ----------------

__global__ __launch_bounds__(256) void k_fc(const float* __restrict__ gsum,
                                            const float* __restrict__ fcW1,
                                            const float* __restrict__ fcb1,
                                            const float* __restrict__ fcW2,
                                            const float* __restrict__ fcb2,
                                            const float* __restrict__ fcW3,
                                            const float* __restrict__ fcb3,
                                            float* __restrict__ out) {
    __shared__ float g[DIM];
    __shared__ float h[DIM];
    int t = threadIdx.x;
    g[t] = fmaxf(gsum[t] * (1.0f / (float)N_NODES), 0.f);
    __syncthreads();
    float acc = fcb1[t];
    for (int k = 0; k < DIM; ++k) acc = fmaf(g[k], fcW1[k * DIM + t], acc);
    h[t] = fmaxf(acc, 0.f);
    __syncthreads();
    acc = fcb2[t];
    for (int k = 0; k < DIM; ++k) acc = fmaf(h[k], fcW2[k * DIM + t], acc);
    __syncthreads();
    g[t] = fmaxf(acc, 0.f);
    __syncthreads();
    if (t < ACT) {
        float o = fcb3[t];
        for (int k = 0; k < DIM; ++k) o = fmaf(g[k], fcW3[k * ACT + t], o);
        out[t] = o;
    }
}

// ---------------- launch ----------------

extern "C" void kernel_launch(void* const* d_in, const int* in_sizes, int n_in,
                              void* d_out, int out_size, void* d_ws, size_t ws_size,
                              hipStream_t stream) {
    const float* x    = (const float*)d_in[0];
    const int*   ei   = (const int*)d_in[1];
    const float* W1   = (const float*)d_in[2];
    const float* b1   = (const float*)d_in[3];
    const float* W2   = (const float*)d_in[4];
    const float* b2   = (const float*)d_in[5];
    const float* fcW1 = (const float*)d_in[6];
    const float* fcb1 = (const float*)d_in[7];
    const float* fcW2 = (const float*)d_in[8];
    const float* fcb2 = (const float*)d_in[9];
    const float* fcW3 = (const float*)d_in[10];
    const float* fcb3 = (const float*)d_in[11];
    float* out = (float*)d_out;

    char* w = (char*)d_ws;
    size_t o = 0;
#define CARVE(name, type, count) \
    type* name = (type*)(w + o); \
    o += (((size_t)(count) * sizeof(type)) + 255) & ~(size_t)255;
    CARVE(degi, int, N_NODES)
    CARVE(rowstart, int, N_NODES + 1)
    CARVE(fillpos, int, N_NODES)
    CARVE(dinv, float, N_NODES)
    CARVE(lexc, int, N_NODES)
    CARVE(btot, int, SCAN_NB)
    CARVE(bbase, int, SCAN_NB)
    CARVE(csr_src, int, N_NODES + N_EDGES)
    CARVE(csr_norm, float, N_NODES + N_EDGES)
    CARVE(gsum, float, DIM)
    CARVE(Hbuf, float, (size_t)N_NODES * DIM)
    CARVE(Xbuf, float, (size_t)N_NODES * DIM)
#undef CARVE

    hipMemsetAsync(gsum, 0, DIM * sizeof(float), stream);

    k_deg_init<<<(N_NODES + 255) / 256, 256, 0, stream>>>(degi);
    k_deg_count<<<(N_EDGES + 255) / 256, 256, 0, stream>>>(ei, degi);
    k_scan_local<<<SCAN_NB, SCAN_B, 0, stream>>>(degi, lexc, btot);
    k_scan_tops<<<1, SCAN_B, 0, stream>>>(btot, bbase, rowstart);
    k_scan_apply<<<SCAN_NB, SCAN_B, 0, stream>>>(degi, lexc, bbase, rowstart, fillpos,
                                                 dinv, csr_src, csr_norm);
    k_fill_edge<<<(N_EDGES + 255) / 256, 256, 0, stream>>>(ei, dinv, fillpos, csr_src, csr_norm);

    int gemm_grid = (N_NODES + BM - 1) / BM;
    k_gemm<<<gemm_grid, 256, 0, stream>>>(x, W1, Hbuf);
    k_agg<<<(N_NODES + 3) / 4, 256, 0, stream>>>(Hbuf, rowstart, csr_src, csr_norm, b1, Xbuf);
    k_gemm<<<gemm_grid, 256, 0, stream>>>(Xbuf, W2, Hbuf);
    k_agg<<<(N_NODES + 3) / 4, 256, 0, stream>>>(Hbuf, rowstart, csr_src, csr_norm, b2, Xbuf);

    k_colsum<<<256, 256, 0, stream>>>(Xbuf, gsum);
    k_fc<<<1, 256, 0, stream>>>(gsum, fcW1, fcb1, fcW2, fcb2, fcW3, fcb3, out);
}

// Round 3
// 405.477 us; speedup vs baseline: 1.7792x; 1.4508x over previous
//
#include <hip/hip_runtime.h>

#define N_NODES 50000
#define N_EDGES 800000
#define DIM 256
#define ACT 64
#define SCAN_B 256
#define SCAN_NB ((N_NODES + SCAN_B - 1) / SCAN_B)   // 196

typedef __attribute__((ext_vector_type(8))) short short8_t;
typedef __attribute__((ext_vector_type(4))) float f32x4;
typedef __attribute__((ext_vector_type(4))) unsigned short ushort4_t;

__device__ __forceinline__ unsigned short f2b(float x) {   // f32 -> bf16 RNE
    unsigned u = __float_as_uint(x);
    unsigned r = u + 0x7FFFu + ((u >> 16) & 1u);
    return (unsigned short)(r >> 16);
}
__device__ __forceinline__ float b2f(unsigned short u) {
    return __uint_as_float(((unsigned)u) << 16);
}

// ---------------- dtype conversion ----------------

__global__ __launch_bounds__(256) void k_cvt_x(const float* __restrict__ x,
                                               unsigned short* __restrict__ xb) {
    // 50000*256 = 12.8M elems, 8 per thread
    int i = blockIdx.x * blockDim.x + threadIdx.x;
    const int TOT = N_NODES * DIM / 8;
    if (i >= TOT) return;
    const float4* src = (const float4*)(x) + i * 2;
    float4 a = src[0], b = src[1];
    ushort4_t lo, hi;
    lo.x = f2b(a.x); lo.y = f2b(a.y); lo.z = f2b(a.z); lo.w = f2b(a.w);
    hi.x = f2b(b.x); hi.y = f2b(b.y); hi.z = f2b(b.z); hi.w = f2b(b.w);
    ushort4_t* dst = (ushort4_t*)(xb) + i * 2;
    dst[0] = lo; dst[1] = hi;
}

// transpose + convert W[k][n] (fp32) -> Wt[n][k] (bf16), 256x256
__global__ __launch_bounds__(256) void k_cvt_wt(const float* __restrict__ W,
                                                unsigned short* __restrict__ Wt) {
    int i = blockIdx.x * blockDim.x + threadIdx.x;   // 65536 threads
    int k = i >> 8, n = i & 255;
    Wt[n * DIM + k] = f2b(W[k * DIM + n]);
}

// ---------------- degree ----------------

__global__ void k_deg_init(int* degi) {
    int i = blockIdx.x * blockDim.x + threadIdx.x;
    if (i < N_NODES) degi[i] = 1;   // self-loop
}

__global__ void k_deg_count(const int* __restrict__ ei, int* degi) {
    int e = blockIdx.x * blockDim.x + threadIdx.x;
    if (e < N_EDGES) atomicAdd(&degi[ei[N_EDGES + e]], 1);  // dst row
}

// ---------------- hierarchical exclusive scan ----------------

__global__ __launch_bounds__(SCAN_B) void k_scan_local(const int* __restrict__ degi,
                                                       int* lexc, int* btot) {
    __shared__ int sm[SCAN_B];
    int t = threadIdx.x;
    int i = blockIdx.x * SCAN_B + t;
    int v = (i < N_NODES) ? degi[i] : 0;
    sm[t] = v;
    __syncthreads();
#pragma unroll
    for (int off = 1; off < SCAN_B; off <<= 1) {
        int u = (t >= off) ? sm[t - off] : 0;
        __syncthreads();
        sm[t] += u;
        __syncthreads();
    }
    if (i < N_NODES) lexc[i] = sm[t] - v;
    if (t == SCAN_B - 1) btot[blockIdx.x] = sm[t];
}

__global__ __launch_bounds__(SCAN_B) void k_scan_tops(const int* __restrict__ btot,
                                                      int* bbase, int* rowstart) {
    __shared__ int sm[SCAN_B];
    int t = threadIdx.x;
    int v = (t < SCAN_NB) ? btot[t] : 0;
    sm[t] = v;
    __syncthreads();
#pragma unroll
    for (int off = 1; off < SCAN_B; off <<= 1) {
        int u = (t >= off) ? sm[t - off] : 0;
        __syncthreads();
        sm[t] += u;
        __syncthreads();
    }
    if (t < SCAN_NB) bbase[t] = sm[t] - v;
    if (t == SCAN_NB - 1) rowstart[N_NODES] = sm[t];
}

__global__ __launch_bounds__(SCAN_B) void k_scan_apply(const int* __restrict__ degi,
                                                       const int* __restrict__ lexc,
                                                       const int* __restrict__ bbase,
                                                       int* rowstart, int* fillpos,
                                                       float* dinv,
                                                       int* csr_src, float* csr_norm) {
    int i = blockIdx.x * SCAN_B + threadIdx.x;
    if (i >= N_NODES) return;
    int rs = bbase[blockIdx.x] + lexc[i];
    rowstart[i] = rs;
    int d = degi[i];
    float di = rsqrtf((float)d);
    dinv[i] = di;
    csr_src[rs] = i;          // self-loop entry first in row
    csr_norm[rs] = di * di;
    fillpos[i] = rs + 1;
}

__global__ void k_fill_edge(const int* __restrict__ ei,
                            const float* __restrict__ dinv, int* fillpos,
                            int* csr_src, float* csr_norm) {
    int e = blockIdx.x * blockDim.x + threadIdx.x;
    if (e < N_EDGES) {
        int s = ei[e];
        int d = ei[N_EDGES + e];
        int p = atomicAdd(&fillpos[d], 1);
        csr_src[p] = s;
        csr_norm[p] = dinv[s] * dinv[d];
    }
}

// ---------------- bf16 MFMA GEMM: H[M,256] = A[M,256] @ Wt^T ----------------
// A bf16 row-major, Wt bf16 [n][k] (pre-transposed W), H bf16 row-major.
// Block: 256 thr (4 waves), tile 64 rows x 256 cols; wave w owns cols [64w,64w+64).
// LDS XOR-swizzle: byte ^= (row&7)<<4  -> fragment ds_read_b128 is 2-way (free).

__global__ __launch_bounds__(256) void k_gemm_mfma(const unsigned short* __restrict__ A,
                                                   const unsigned short* __restrict__ Wt,
                                                   unsigned short* __restrict__ H,
                                                   int M) {
    __shared__ char lds[40960];          // As 64x64 bf16 (8KB) + Bs 256x64 bf16 (32KB)
    char* AsB = lds;
    char* BsB = lds + 8192;

    int tid = threadIdx.x;
    int w = tid >> 6;
    int l = tid & 63;
    int r0 = blockIdx.x * 64;

    f32x4 acc[4][4];
#pragma unroll
    for (int i = 0; i < 4; ++i)
#pragma unroll
        for (int j = 0; j < 4; ++j) acc[i][j] = (f32x4)(0.f);

    for (int kt = 0; kt < 4; ++kt) {
        int k0 = kt * 64;
        // stage A: 64 rows x 64 bf16 = 512 x 16B chunks, 2 per thread
#pragma unroll
        for (int i = 0; i < 2; ++i) {
            int c = tid + i * 256;
            int row = c >> 3, kc = c & 7;
            int g = r0 + row; if (g >= M) g = M - 1;
            short8_t v = *(const short8_t*)(A + (size_t)g * DIM + k0 + kc * 8);
            int off = (row * 128 + kc * 16) ^ ((row & 7) << 4);
            *(short8_t*)(AsB + off) = v;
        }
        // stage B: 256 rows x 64 bf16 = 2048 chunks, 8 per thread
#pragma unroll
        for (int i = 0; i < 8; ++i) {
            int c = tid + i * 256;
            int n = c >> 3, kc = c & 7;
            short8_t v = *(const short8_t*)(Wt + n * DIM + k0 + kc * 8);
            int off = (n * 128 + kc * 16) ^ ((n & 7) << 4);
            *(short8_t*)(BsB + off) = v;
        }
        __syncthreads();

#pragma unroll
        for (int kf = 0; kf < 2; ++kf) {
            int kb = kf * 64 + (l >> 4) * 16;   // byte offset of this lane's 8 bf16 in row
            short8_t a[4], b[4];
#pragma unroll
            for (int fm = 0; fm < 4; ++fm) {
                int ra = fm * 16 + (l & 15);
                a[fm] = *(const short8_t*)(AsB + ((ra * 128 + kb) ^ ((ra & 7) << 4)));
            }
#pragma unroll
            for (int fn = 0; fn < 4; ++fn) {
                int nb = w * 64 + fn * 16 + (l & 15);
                b[fn] = *(const short8_t*)(BsB + ((nb * 128 + kb) ^ ((nb & 7) << 4)));
            }
#pragma unroll
            for (int fm = 0; fm < 4; ++fm)
#pragma unroll
                for (int fn = 0; fn < 4; ++fn)
                    acc[fm][fn] = __builtin_amdgcn_mfma_f32_16x16x32_bf16(
                        a[fm], b[fn], acc[fm][fn], 0, 0, 0);
        }
        __syncthreads();
    }

    // C/D layout: col = l&15, row = (l>>4)*4 + i
#pragma unroll
    for (int fm = 0; fm < 4; ++fm) {
#pragma unroll
        for (int i = 0; i < 4; ++i) {
            int row = r0 + fm * 16 + ((l >> 4) << 2) + i;
            if (row >= M) continue;
#pragma unroll
            for (int fn = 0; fn < 4; ++fn) {
                int col = w * 64 + fn * 16 + (l & 15);
                H[(size_t)row * DIM + col] = f2b(acc[fm][fn][i]);
            }
        }
    }
}

// ---------------- aggregation: one wave per node, bf16 gather, fused bias+ReLU ----------------

__global__ __launch_bounds__(256) void k_agg(const unsigned short* __restrict__ H,
                                             const int* __restrict__ rowstart,
                                             const int* __restrict__ csr_src,
                                             const float* __restrict__ csr_norm,
                                             const float* __restrict__ bias,
                                             unsigned short* __restrict__ X) {
    int wid = (blockIdx.x * blockDim.x + threadIdx.x) >> 6;  // node id
    int lane = threadIdx.x & 63;
    if (wid >= N_NODES) return;
    int beg = rowstart[wid];
    int end = rowstart[wid + 1];
    float ax = 0.f, ay = 0.f, az = 0.f, aw = 0.f;
    for (int e = beg; e < end; ++e) {
        int s = csr_src[e];
        float nm = csr_norm[e];
        ushort4_t v = *(const ushort4_t*)(H + (size_t)s * DIM + (lane << 2));
        ax = fmaf(nm, b2f(v.x), ax);
        ay = fmaf(nm, b2f(v.y), ay);
        az = fmaf(nm, b2f(v.z), az);
        aw = fmaf(nm, b2f(v.w), aw);
    }
    float4 bb = *(const float4*)&bias[lane << 2];
    ushort4_t o;
    o.x = f2b(fmaxf(ax + bb.x, 0.f));
    o.y = f2b(fmaxf(ay + bb.y, 0.f));
    o.z = f2b(fmaxf(az + bb.z, 0.f));
    o.w = f2b(fmaxf(aw + bb.w, 0.f));
    *(ushort4_t*)(X + (size_t)wid * DIM + (lane << 2)) = o;
}

// ---------------- column sum for mean-pool (bf16 in, fp32 acc) ----------------

__global__ __launch_bounds__(256) void k_colsum(const unsigned short* __restrict__ X,
                                                float* gsum) {
    int t = threadIdx.x;
    int b = blockIdx.x;
    const int RPB = (N_NODES + 255) / 256;  // 196
    int r0 = b * RPB;
    int r1 = r0 + RPB; if (r1 > N_NODES) r1 = N_NODES;
    float acc = 0.f;
    for (int r = r0; r < r1; ++r) acc += b2f(X[(size_t)r * DIM + t]);
    atomicAdd(&gsum[t], acc);
}

// ---------------- FC head (single block, fp32) ----------------

__global__ __launch_bounds__(256) void k_fc(const float* __restrict__ gsum,
                                            const float* __restrict__ fcW1,
                                            const float* __restrict__ fcb1,
                                            const float* __restrict__ fcW2,
                                            const float* __restrict__ fcb2,
                                            const float* __restrict__ fcW3,
                                            const float* __restrict__ fcb3,
                                            float* __restrict__ out) {
    __shared__ float g[DIM];
    __shared__ float h[DIM];
    int t = threadIdx.x;
    g[t] = fmaxf(gsum[t] * (1.0f / (float)N_NODES), 0.f);
    __syncthreads();
    float acc = fcb1[t];
    for (int k = 0; k < DIM; ++k) acc = fmaf(g[k], fcW1[k * DIM + t], acc);
    h[t] = fmaxf(acc, 0.f);
    __syncthreads();
    acc = fcb2[t];
    for (int k = 0; k < DIM; ++k) acc = fmaf(h[k], fcW2[k * DIM + t], acc);
    __syncthreads();
    g[t] = fmaxf(acc, 0.f);
    __syncthreads();
    if (t < ACT) {
        float o = fcb3[t];
        for (int k = 0; k < DIM; ++k) o = fmaf(g[k], fcW3[k * ACT + t], o);
        out[t] = o;
    }
}

// ---------------- launch ----------------

extern "C" void kernel_launch(void* const* d_in, const int* in_sizes, int n_in,
                              void* d_out, int out_size, void* d_ws, size_t ws_size,
                              hipStream_t stream) {
    const float* x    = (const float*)d_in[0];
    const int*   ei   = (const int*)d_in[1];
    const float* W1   = (const float*)d_in[2];
    const float* b1   = (const float*)d_in[3];
    const float* W2   = (const float*)d_in[4];
    const float* b2   = (const float*)d_in[5];
    const float* fcW1 = (const float*)d_in[6];
    const float* fcb1 = (const float*)d_in[7];
    const float* fcW2 = (const float*)d_in[8];
    const float* fcb2 = (const float*)d_in[9];
    const float* fcW3 = (const float*)d_in[10];
    const float* fcb3 = (const float*)d_in[11];
    float* out = (float*)d_out;

    char* w = (char*)d_ws;
    size_t o = 0;
#define CARVE(name, type, count) \
    type* name = (type*)(w + o); \
    o += (((size_t)(count) * sizeof(type)) + 255) & ~(size_t)255;
    CARVE(degi, int, N_NODES)
    CARVE(rowstart, int, N_NODES + 1)
    CARVE(fillpos, int, N_NODES)
    CARVE(dinv, float, N_NODES)
    CARVE(lexc, int, N_NODES)
    CARVE(btot, int, SCAN_NB)
    CARVE(bbase, int, SCAN_NB)
    CARVE(csr_src, int, N_NODES + N_EDGES)
    CARVE(csr_norm, float, N_NODES + N_EDGES)
    CARVE(gsum, float, DIM)
    CARVE(xb,  unsigned short, (size_t)N_NODES * DIM)   // x in bf16
    CARVE(W1t, unsigned short, DIM * DIM)               // W1^T bf16
    CARVE(W2t, unsigned short, DIM * DIM)               // W2^T bf16
    CARVE(Hbuf, unsigned short, (size_t)N_NODES * DIM)  // h = A@W  (bf16)
    CARVE(Xbuf, unsigned short, (size_t)N_NODES * DIM)  // aggregated (bf16)
#undef CARVE

    hipMemsetAsync(gsum, 0, DIM * sizeof(float), stream);

    // dtype prep
    k_cvt_x<<<(N_NODES * DIM / 8 + 255) / 256, 256, 0, stream>>>(x, xb);
    k_cvt_wt<<<DIM * DIM / 256, 256, 0, stream>>>(W1, W1t);
    k_cvt_wt<<<DIM * DIM / 256, 256, 0, stream>>>(W2, W2t);

    // CSR build
    k_deg_init<<<(N_NODES + 255) / 256, 256, 0, stream>>>(degi);
    k_deg_count<<<(N_EDGES + 255) / 256, 256, 0, stream>>>(ei, degi);
    k_scan_local<<<SCAN_NB, SCAN_B, 0, stream>>>(degi, lexc, btot);
    k_scan_tops<<<1, SCAN_B, 0, stream>>>(btot, bbase, rowstart);
    k_scan_apply<<<SCAN_NB, SCAN_B, 0, stream>>>(degi, lexc, bbase, rowstart, fillpos,
                                                 dinv, csr_src, csr_norm);
    k_fill_edge<<<(N_EDGES + 255) / 256, 256, 0, stream>>>(ei, dinv, fillpos, csr_src, csr_norm);

    // layer 1
    int gemm_grid = (N_NODES + 63) / 64;   // 782
    k_gemm_mfma<<<gemm_grid, 256, 0, stream>>>(xb, W1t, Hbuf, N_NODES);
    k_agg<<<(N_NODES + 3) / 4, 256, 0, stream>>>(Hbuf, rowstart, csr_src, csr_norm, b1, Xbuf);
    // layer 2
    k_gemm_mfma<<<gemm_grid, 256, 0, stream>>>(Xbuf, W2t, Hbuf, N_NODES);
    k_agg<<<(N_NODES + 3) / 4, 256, 0, stream>>>(Hbuf, rowstart, csr_src, csr_norm, b2, Xbuf);

    // pool + head
    k_colsum<<<256, 256, 0, stream>>>(Xbuf, gsum);
    k_fc<<<1, 256, 0, stream>>>(gsum, fcW1, fcb1, fcW2, fcb2, fcW3, fcb3, out);
}

// Round 4
// 336.867 us; speedup vs baseline: 2.1416x; 1.2037x over previous
//
#include <hip/hip_runtime.h>

#define N_NODES 50000
#define N_EDGES 800000
#define DIM 256
#define ACT 64
#define SCAN_B 256
#define SCAN_NB ((N_NODES + SCAN_B - 1) / SCAN_B)   // 196
#define SLICE_ELEMS ((size_t)N_NODES * 32)          // elems per 32-dim slice
#define AGG_CHUNKS 256
#define NPC ((N_NODES + AGG_CHUNKS - 1) / AGG_CHUNKS)  // 196 nodes per chunk

typedef __attribute__((ext_vector_type(8))) short short8_t;
typedef __attribute__((ext_vector_type(4))) float f32x4;
typedef __attribute__((ext_vector_type(4))) unsigned short ushort4_t;
typedef __attribute__((ext_vector_type(2))) unsigned short ushort2_t;

__device__ __forceinline__ unsigned short f2b(float x) {   // f32 -> bf16 RNE
    unsigned u = __float_as_uint(x);
    unsigned r = u + 0x7FFFu + ((u >> 16) & 1u);
    return (unsigned short)(r >> 16);
}
__device__ __forceinline__ float b2f(unsigned short u) {
    return __uint_as_float(((unsigned)u) << 16);
}

// ---------------- dtype conversion ----------------

// x fp32 row-major -> bf16 SLICED [slice][node][32]
__global__ __launch_bounds__(256) void k_cvt_x(const float* __restrict__ x,
                                               unsigned short* __restrict__ xb) {
    int i = blockIdx.x * blockDim.x + threadIdx.x;   // one thread = 8 elems
    const int TOT = N_NODES * DIM / 8;
    if (i >= TOT) return;
    const float4* src = (const float4*)(x) + (size_t)i * 2;
    float4 a = src[0], b = src[1];
    int row = i >> 5;
    int col0 = (i << 3) & 255;
    int slice = col0 >> 5, within = col0 & 31;
    ushort4_t lo, hi;
    lo.x = f2b(a.x); lo.y = f2b(a.y); lo.z = f2b(a.z); lo.w = f2b(a.w);
    hi.x = f2b(b.x); hi.y = f2b(b.y); hi.z = f2b(b.z); hi.w = f2b(b.w);
    ushort4_t* dst = (ushort4_t*)(xb + (size_t)slice * SLICE_ELEMS + (size_t)row * 32 + within);
    dst[0] = lo; dst[1] = hi;
}

// transpose + convert W[k][n] (fp32) -> Wt[n][k] (bf16), 256x256
__global__ __launch_bounds__(256) void k_cvt_wt(const float* __restrict__ W,
                                                unsigned short* __restrict__ Wt) {
    int i = blockIdx.x * blockDim.x + threadIdx.x;
    int k = i >> 8, n = i & 255;
    Wt[n * DIM + k] = f2b(W[k * DIM + n]);
}

// ---------------- degree ----------------

__global__ void k_deg_init(int* degi) {
    int i = blockIdx.x * blockDim.x + threadIdx.x;
    if (i < N_NODES) degi[i] = 1;   // self-loop
}

__global__ void k_deg_count(const int* __restrict__ ei, int* degi) {
    int e = blockIdx.x * blockDim.x + threadIdx.x;
    if (e < N_EDGES) atomicAdd(&degi[ei[N_EDGES + e]], 1);  // dst row
}

// ---------------- hierarchical exclusive scan ----------------

__global__ __launch_bounds__(SCAN_B) void k_scan_local(const int* __restrict__ degi,
                                                       int* lexc, int* btot) {
    __shared__ int sm[SCAN_B];
    int t = threadIdx.x;
    int i = blockIdx.x * SCAN_B + t;
    int v = (i < N_NODES) ? degi[i] : 0;
    sm[t] = v;
    __syncthreads();
#pragma unroll
    for (int off = 1; off < SCAN_B; off <<= 1) {
        int u = (t >= off) ? sm[t - off] : 0;
        __syncthreads();
        sm[t] += u;
        __syncthreads();
    }
    if (i < N_NODES) lexc[i] = sm[t] - v;
    if (t == SCAN_B - 1) btot[blockIdx.x] = sm[t];
}

__global__ __launch_bounds__(SCAN_B) void k_scan_tops(const int* __restrict__ btot,
                                                      int* bbase, int* rowstart) {
    __shared__ int sm[SCAN_B];
    int t = threadIdx.x;
    int v = (t < SCAN_NB) ? btot[t] : 0;
    sm[t] = v;
    __syncthreads();
#pragma unroll
    for (int off = 1; off < SCAN_B; off <<= 1) {
        int u = (t >= off) ? sm[t - off] : 0;
        __syncthreads();
        sm[t] += u;
        __syncthreads();
    }
    if (t < SCAN_NB) bbase[t] = sm[t] - v;
    if (t == SCAN_NB - 1) rowstart[N_NODES] = sm[t];
}

__global__ __launch_bounds__(SCAN_B) void k_scan_apply(const int* __restrict__ degi,
                                                       const int* __restrict__ lexc,
                                                       const int* __restrict__ bbase,
                                                       int* rowstart, int* fillpos,
                                                       float* dinv, int2* csr_pair) {
    int i = blockIdx.x * SCAN_B + threadIdx.x;
    if (i >= N_NODES) return;
    int rs = bbase[blockIdx.x] + lexc[i];
    rowstart[i] = rs;
    int d = degi[i];
    float di = rsqrtf((float)d);
    dinv[i] = di;
    int2 p; p.x = i; p.y = __float_as_int(di * di);
    csr_pair[rs] = p;          // self-loop entry first in row
    fillpos[i] = rs + 1;
}

__global__ void k_fill_edge(const int* __restrict__ ei,
                            const float* __restrict__ dinv, int* fillpos,
                            int2* csr_pair) {
    int e = blockIdx.x * blockDim.x + threadIdx.x;
    if (e < N_EDGES) {
        int s = ei[e];
        int d = ei[N_EDGES + e];
        int p = atomicAdd(&fillpos[d], 1);
        int2 pr; pr.x = s; pr.y = __float_as_int(dinv[s] * dinv[d]);
        csr_pair[p] = pr;
    }
}

// ---------------- bf16 MFMA GEMM: H = A @ Wt^T  (A, H in SLICED layout) ----------------

__global__ __launch_bounds__(256) void k_gemm_mfma(const unsigned short* __restrict__ A,
                                                   const unsigned short* __restrict__ Wt,
                                                   unsigned short* __restrict__ H,
                                                   int M) {
    __shared__ char lds[40960];          // As 64x64 bf16 (8KB) + Bs 256x64 bf16 (32KB)
    char* AsB = lds;
    char* BsB = lds + 8192;

    int tid = threadIdx.x;
    int w = tid >> 6;
    int l = tid & 63;
    int r0 = blockIdx.x * 64;

    f32x4 acc[4][4];
#pragma unroll
    for (int i = 0; i < 4; ++i)
#pragma unroll
        for (int j = 0; j < 4; ++j) acc[i][j] = (f32x4)(0.f);

    for (int kt = 0; kt < 4; ++kt) {
        int k0 = kt * 64;
        // stage A from sliced layout: 64 rows x 64 bf16, 2 x 16B chunks/thread
#pragma unroll
        for (int i = 0; i < 2; ++i) {
            int c = tid + i * 256;
            int row = c >> 3, kc = c & 7;
            int k = k0 + kc * 8;
            int slice = k >> 5, within = k & 31;
            int g = r0 + row; if (g >= M) g = M - 1;
            short8_t v = *(const short8_t*)(A + (size_t)slice * SLICE_ELEMS + (size_t)g * 32 + within);
            int off = (row * 128 + kc * 16) ^ ((row & 7) << 4);
            *(short8_t*)(AsB + off) = v;
        }
        // stage B: 256 rows x 64 bf16 = 2048 chunks, 8 per thread
#pragma unroll
        for (int i = 0; i < 8; ++i) {
            int c = tid + i * 256;
            int n = c >> 3, kc = c & 7;
            short8_t v = *(const short8_t*)(Wt + n * DIM + k0 + kc * 8);
            int off = (n * 128 + kc * 16) ^ ((n & 7) << 4);
            *(short8_t*)(BsB + off) = v;
        }
        __syncthreads();

#pragma unroll
        for (int kf = 0; kf < 2; ++kf) {
            int kb = kf * 64 + (l >> 4) * 16;
            short8_t a[4], b[4];
#pragma unroll
            for (int fm = 0; fm < 4; ++fm) {
                int ra = fm * 16 + (l & 15);
                a[fm] = *(const short8_t*)(AsB + ((ra * 128 + kb) ^ ((ra & 7) << 4)));
            }
#pragma unroll
            for (int fn = 0; fn < 4; ++fn) {
                int nb = w * 64 + fn * 16 + (l & 15);
                b[fn] = *(const short8_t*)(BsB + ((nb * 128 + kb) ^ ((nb & 7) << 4)));
            }
#pragma unroll
            for (int fm = 0; fm < 4; ++fm)
#pragma unroll
                for (int fn = 0; fn < 4; ++fn)
                    acc[fm][fn] = __builtin_amdgcn_mfma_f32_16x16x32_bf16(
                        a[fm], b[fn], acc[fm][fn], 0, 0, 0);
        }
        __syncthreads();
    }

    // C/D layout: col = l&15, row = (l>>4)*4 + i ; write SLICED
#pragma unroll
    for (int fm = 0; fm < 4; ++fm) {
#pragma unroll
        for (int i = 0; i < 4; ++i) {
            int row = r0 + fm * 16 + ((l >> 4) << 2) + i;
            if (row >= M) continue;
#pragma unroll
            for (int fn = 0; fn < 4; ++fn) {
                int col = w * 64 + fn * 16 + (l & 15);
                int slice = col >> 5;
                H[(size_t)slice * SLICE_ELEMS + (size_t)row * 32 + (col & 31)] = f2b(acc[fm][fn][i]);
            }
        }
    }
}

// ---------------- sliced aggregation: 16-lane group per node, fused bias+ReLU ----------------
// grid = 8 slices x 256 chunks; blockIdx%8 = slice -> pins slice to one XCD's L2.
// Optionally accumulates the column sum (mean-pool) and skips the X write.

__global__ __launch_bounds__(256) void k_agg_sliced(const unsigned short* __restrict__ H,
                                                    const int* __restrict__ rowstart,
                                                    const int2* __restrict__ csr_pair,
                                                    const float* __restrict__ bias,
                                                    unsigned short* __restrict__ X,
                                                    float* __restrict__ gsum,
                                                    int write_out) {
    int slice = blockIdx.x & 7;
    int chunk = blockIdx.x >> 3;
    int g = threadIdx.x >> 4;        // 16 groups
    int lane = threadIdx.x & 15;
    const unsigned short* Hs = H + (size_t)slice * SLICE_ELEMS;
    unsigned short* Xs = X + (size_t)slice * SLICE_ELEMS;
    int d0 = slice * 32 + lane * 2;
    float b0 = bias[d0], b1 = bias[d0 + 1];
    float c0 = 0.f, c1 = 0.f;
    int nEnd = (chunk + 1) * NPC; if (nEnd > N_NODES) nEnd = N_NODES;
    for (int n = chunk * NPC + g; n < nEnd; n += 16) {
        int beg = rowstart[n], end = rowstart[n + 1];
        float a0 = 0.f, a1 = 0.f;
        int e = beg;
        for (; e + 3 < end; e += 4) {
            int2 p0 = csr_pair[e], p1 = csr_pair[e + 1];
            int2 p2 = csr_pair[e + 2], p3 = csr_pair[e + 3];
            ushort2_t v0 = *(const ushort2_t*)(Hs + (size_t)p0.x * 32 + lane * 2);
            ushort2_t v1 = *(const ushort2_t*)(Hs + (size_t)p1.x * 32 + lane * 2);
            ushort2_t v2 = *(const ushort2_t*)(Hs + (size_t)p2.x * 32 + lane * 2);
            ushort2_t v3 = *(const ushort2_t*)(Hs + (size_t)p3.x * 32 + lane * 2);
            float n0 = __int_as_float(p0.y), n1 = __int_as_float(p1.y);
            float n2 = __int_as_float(p2.y), n3 = __int_as_float(p3.y);
            a0 = fmaf(n0, b2f(v0.x), a0); a1 = fmaf(n0, b2f(v0.y), a1);
            a0 = fmaf(n1, b2f(v1.x), a0); a1 = fmaf(n1, b2f(v1.y), a1);
            a0 = fmaf(n2, b2f(v2.x), a0); a1 = fmaf(n2, b2f(v2.y), a1);
            a0 = fmaf(n3, b2f(v3.x), a0); a1 = fmaf(n3, b2f(v3.y), a1);
        }
        for (; e < end; ++e) {
            int2 p = csr_pair[e];
            ushort2_t v = *(const ushort2_t*)(Hs + (size_t)p.x * 32 + lane * 2);
            float nm = __int_as_float(p.y);
            a0 = fmaf(nm, b2f(v.x), a0); a1 = fmaf(nm, b2f(v.y), a1);
        }
        float o0 = fmaxf(a0 + b0, 0.f);
        float o1 = fmaxf(a1 + b1, 0.f);
        if (write_out) {
            ushort2_t o; o.x = f2b(o0); o.y = f2b(o1);
            *(ushort2_t*)(Xs + (size_t)n * 32 + lane * 2) = o;
        }
        c0 += o0; c1 += o1;
    }
    if (gsum) {
        __shared__ float sm0[256], sm1[256];
        int tid = threadIdx.x;
        sm0[tid] = c0; sm1[tid] = c1;
        __syncthreads();
#pragma unroll
        for (int off = 8; off >= 1; off >>= 1) {
            if (g < off) {
                sm0[tid] += sm0[tid + off * 16];
                sm1[tid] += sm1[tid + off * 16];
            }
            __syncthreads();
        }
        if (g == 0) {
            atomicAdd(&gsum[d0], sm0[lane]);
            atomicAdd(&gsum[d0 + 1], sm1[lane]);
        }
    }
}

// ---------------- FC head (single block, fp32) ----------------

__global__ __launch_bounds__(256) void k_fc(const float* __restrict__ gsum,
                                            const float* __restrict__ fcW1,
                                            const float* __restrict__ fcb1,
                                            const float* __restrict__ fcW2,
                                            const float* __restrict__ fcb2,
                                            const float* __restrict__ fcW3,
                                            const float* __restrict__ fcb3,
                                            float* __restrict__ out) {
    __shared__ float g[DIM];
    __shared__ float h[DIM];
    int t = threadIdx.x;
    g[t] = fmaxf(gsum[t] * (1.0f / (float)N_NODES), 0.f);
    __syncthreads();
    float acc = fcb1[t];
    for (int k = 0; k < DIM; ++k) acc = fmaf(g[k], fcW1[k * DIM + t], acc);
    h[t] = fmaxf(acc, 0.f);
    __syncthreads();
    acc = fcb2[t];
    for (int k = 0; k < DIM; ++k) acc = fmaf(h[k], fcW2[k * DIM + t], acc);
    __syncthreads();
    g[t] = fmaxf(acc, 0.f);
    __syncthreads();
    if (t < ACT) {
        float o = fcb3[t];
        for (int k = 0; k < DIM; ++k) o = fmaf(g[k], fcW3[k * ACT + t], o);
        out[t] = o;
    }
}

// ---------------- launch ----------------

extern "C" void kernel_launch(void* const* d_in, const int* in_sizes, int n_in,
                              void* d_out, int out_size, void* d_ws, size_t ws_size,
                              hipStream_t stream) {
    const float* x    = (const float*)d_in[0];
    const int*   ei   = (const int*)d_in[1];
    const float* W1   = (const float*)d_in[2];
    const float* b1   = (const float*)d_in[3];
    const float* W2   = (const float*)d_in[4];
    const float* b2   = (const float*)d_in[5];
    const float* fcW1 = (const float*)d_in[6];
    const float* fcb1 = (const float*)d_in[7];
    const float* fcW2 = (const float*)d_in[8];
    const float* fcb2 = (const float*)d_in[9];
    const float* fcW3 = (const float*)d_in[10];
    const float* fcb3 = (const float*)d_in[11];
    float* out = (float*)d_out;

    char* w = (char*)d_ws;
    size_t o = 0;
#define CARVE(name, type, count) \
    type* name = (type*)(w + o); \
    o += (((size_t)(count) * sizeof(type)) + 255) & ~(size_t)255;
    CARVE(degi, int, N_NODES)
    CARVE(rowstart, int, N_NODES + 1)
    CARVE(fillpos, int, N_NODES)
    CARVE(dinv, float, N_NODES)
    CARVE(lexc, int, N_NODES)
    CARVE(btot, int, SCAN_NB)
    CARVE(bbase, int, SCAN_NB)
    CARVE(csr_pair, int2, N_NODES + N_EDGES)
    CARVE(gsum, float, DIM)
    CARVE(xb,  unsigned short, (size_t)N_NODES * DIM)   // x bf16 sliced
    CARVE(W1t, unsigned short, DIM * DIM)
    CARVE(W2t, unsigned short, DIM * DIM)
    CARVE(Hbuf, unsigned short, (size_t)N_NODES * DIM)  // bf16 sliced
    CARVE(Xbuf, unsigned short, (size_t)N_NODES * DIM)  // bf16 sliced
#undef CARVE

    hipMemsetAsync(gsum, 0, DIM * sizeof(float), stream);

    // dtype prep
    k_cvt_x<<<(N_NODES * DIM / 8 + 255) / 256, 256, 0, stream>>>(x, xb);
    k_cvt_wt<<<DIM * DIM / 256, 256, 0, stream>>>(W1, W1t);
    k_cvt_wt<<<DIM * DIM / 256, 256, 0, stream>>>(W2, W2t);

    // CSR build
    k_deg_init<<<(N_NODES + 255) / 256, 256, 0, stream>>>(degi);
    k_deg_count<<<(N_EDGES + 255) / 256, 256, 0, stream>>>(ei, degi);
    k_scan_local<<<SCAN_NB, SCAN_B, 0, stream>>>(degi, lexc, btot);
    k_scan_tops<<<1, SCAN_B, 0, stream>>>(btot, bbase, rowstart);
    k_scan_apply<<<SCAN_NB, SCAN_B, 0, stream>>>(degi, lexc, bbase, rowstart, fillpos,
                                                 dinv, csr_pair);
    k_fill_edge<<<(N_EDGES + 255) / 256, 256, 0, stream>>>(ei, dinv, fillpos, csr_pair);

    // layer 1
    int gemm_grid = (N_NODES + 63) / 64;   // 782
    k_gemm_mfma<<<gemm_grid, 256, 0, stream>>>(xb, W1t, Hbuf, N_NODES);
    k_agg_sliced<<<8 * AGG_CHUNKS, 256, 0, stream>>>(Hbuf, rowstart, csr_pair, b1,
                                                     Xbuf, (float*)nullptr, 1);
    // layer 2 (agg fuses mean-pool column sum, no X write)
    k_gemm_mfma<<<gemm_grid, 256, 0, stream>>>(Xbuf, W2t, Hbuf, N_NODES);
    k_agg_sliced<<<8 * AGG_CHUNKS, 256, 0, stream>>>(Hbuf, rowstart, csr_pair, b2,
                                                     Xbuf, gsum, 0);

    // head
    k_fc<<<1, 256, 0, stream>>>(gsum, fcW1, fcb1, fcW2, fcb2, fcW3, fcb3, out);
}

// Round 5
// 322.810 us; speedup vs baseline: 2.2348x; 1.0435x over previous
//
#include <hip/hip_runtime.h>

#define N_NODES 50000
#define N_EDGES 800000
#define DIM 256
#define ACT 64
#define SCAN_B 256
#define SCAN_NB ((N_NODES + SCAN_B - 1) / SCAN_B)   // 196
#define SLICE_ELEMS ((size_t)N_NODES * 32)          // elems per 32-dim slice
#define AGG_CHUNKS 256
#define NPC ((N_NODES + AGG_CHUNKS - 1) / AGG_CHUNKS)  // 196 nodes per chunk

typedef __attribute__((ext_vector_type(8))) short short8_t;
typedef __attribute__((ext_vector_type(4))) float f32x4;
typedef __attribute__((ext_vector_type(4))) unsigned short ushort4_t;
typedef __attribute__((ext_vector_type(2))) unsigned short ushort2_t;

__device__ __forceinline__ unsigned short f2b(float x) {   // f32 -> bf16 RNE
    unsigned u = __float_as_uint(x);
    unsigned r = u + 0x7FFFu + ((u >> 16) & 1u);
    return (unsigned short)(r >> 16);
}
__device__ __forceinline__ float b2f(unsigned short u) {
    return __uint_as_float(((unsigned)u) << 16);
}

// ---------------- dtype conversion ----------------

// x fp32 row-major -> bf16 SLICED [slice][node][32]
__global__ __launch_bounds__(256) void k_cvt_x(const float* __restrict__ x,
                                               unsigned short* __restrict__ xb) {
    int i = blockIdx.x * blockDim.x + threadIdx.x;   // one thread = 8 elems
    const int TOT = N_NODES * DIM / 8;
    if (i >= TOT) return;
    const float4* src = (const float4*)(x) + (size_t)i * 2;
    float4 a = src[0], b = src[1];
    int row = i >> 5;
    int col0 = (i << 3) & 255;
    int slice = col0 >> 5, within = col0 & 31;
    ushort4_t lo, hi;
    lo.x = f2b(a.x); lo.y = f2b(a.y); lo.z = f2b(a.z); lo.w = f2b(a.w);
    hi.x = f2b(b.x); hi.y = f2b(b.y); hi.z = f2b(b.z); hi.w = f2b(b.w);
    ushort4_t* dst = (ushort4_t*)(xb + (size_t)slice * SLICE_ELEMS + (size_t)row * 32 + within);
    dst[0] = lo; dst[1] = hi;
}

// transpose + convert both W1,W2 [k][n] fp32 -> Wt [n][k] bf16
__global__ __launch_bounds__(256) void k_cvt_wt2(const float* __restrict__ W1,
                                                 const float* __restrict__ W2,
                                                 unsigned short* __restrict__ W1t,
                                                 unsigned short* __restrict__ W2t) {
    int b = blockIdx.x;
    const float* W = (b < 256) ? W1 : W2;
    unsigned short* Wt = (b < 256) ? W1t : W2t;
    int i = (b & 255) * 256 + threadIdx.x;
    int k = i >> 8, n = i & 255;
    Wt[n * DIM + k] = f2b(W[k * DIM + n]);
}

// ---------------- degree (degi pre-zeroed; self-loop accounted as +1 in scan) ----------------

__global__ void k_deg_count(const int* __restrict__ ei, int* degi) {
    int e = blockIdx.x * blockDim.x + threadIdx.x;
    if (e < N_EDGES) atomicAdd(&degi[ei[N_EDGES + e]], 1);  // dst row
}

// ---------------- hierarchical exclusive scan ----------------

__global__ __launch_bounds__(SCAN_B) void k_scan_local(const int* __restrict__ degi,
                                                       int* lexc, int* btot) {
    __shared__ int sm[SCAN_B];
    int t = threadIdx.x;
    int i = blockIdx.x * SCAN_B + t;
    int v = (i < N_NODES) ? (degi[i] + 1) : 0;   // +1 = self-loop
    sm[t] = v;
    __syncthreads();
#pragma unroll
    for (int off = 1; off < SCAN_B; off <<= 1) {
        int u = (t >= off) ? sm[t - off] : 0;
        __syncthreads();
        sm[t] += u;
        __syncthreads();
    }
    if (i < N_NODES) lexc[i] = sm[t] - v;
    if (t == SCAN_B - 1) btot[blockIdx.x] = sm[t];
}

__global__ __launch_bounds__(SCAN_B) void k_scan_tops(const int* __restrict__ btot,
                                                      int* bbase, int* rowstart) {
    __shared__ int sm[SCAN_B];
    int t = threadIdx.x;
    int v = (t < SCAN_NB) ? btot[t] : 0;
    sm[t] = v;
    __syncthreads();
#pragma unroll
    for (int off = 1; off < SCAN_B; off <<= 1) {
        int u = (t >= off) ? sm[t - off] : 0;
        __syncthreads();
        sm[t] += u;
        __syncthreads();
    }
    if (t < SCAN_NB) bbase[t] = sm[t] - v;
    if (t == SCAN_NB - 1) rowstart[N_NODES] = sm[t];
}

__global__ __launch_bounds__(SCAN_B) void k_scan_apply(const int* __restrict__ degi,
                                                       const int* __restrict__ lexc,
                                                       const int* __restrict__ bbase,
                                                       int* rowstart, int* fillpos,
                                                       float* dinv, int2* csr_pair) {
    int i = blockIdx.x * SCAN_B + threadIdx.x;
    if (i >= N_NODES) return;
    int rs = bbase[blockIdx.x] + lexc[i];
    rowstart[i] = rs;
    int d = degi[i] + 1;
    float di = rsqrtf((float)d);
    dinv[i] = di;
    int2 p; p.x = i; p.y = __float_as_int(di * di);
    csr_pair[rs] = p;          // self-loop entry first in row
    fillpos[i] = rs + 1;
}

__global__ void k_fill_edge(const int* __restrict__ ei,
                            const float* __restrict__ dinv, int* fillpos,
                            int2* csr_pair) {
    int e = blockIdx.x * blockDim.x + threadIdx.x;
    if (e < N_EDGES) {
        int s = ei[e];
        int d = ei[N_EDGES + e];
        int p = atomicAdd(&fillpos[d], 1);
        int2 pr; pr.x = s; pr.y = __float_as_int(dinv[s] * dinv[d]);
        csr_pair[p] = pr;
    }
}

// ---------------- bf16 MFMA GEMM: H = A @ Wt^T  (A, H in SLICED layout) ----------------

__global__ __launch_bounds__(256) void k_gemm_mfma(const unsigned short* __restrict__ A,
                                                   const unsigned short* __restrict__ Wt,
                                                   unsigned short* __restrict__ H,
                                                   int M) {
    __shared__ char lds[40960];          // As 64x64 bf16 (8KB) + Bs 256x64 bf16 (32KB)
    char* AsB = lds;
    char* BsB = lds + 8192;

    int tid = threadIdx.x;
    int w = tid >> 6;
    int l = tid & 63;
    int r0 = blockIdx.x * 64;

    f32x4 acc[4][4];
#pragma unroll
    for (int i = 0; i < 4; ++i)
#pragma unroll
        for (int j = 0; j < 4; ++j) acc[i][j] = (f32x4)(0.f);

    for (int kt = 0; kt < 4; ++kt) {
        int k0 = kt * 64;
#pragma unroll
        for (int i = 0; i < 2; ++i) {
            int c = tid + i * 256;
            int row = c >> 3, kc = c & 7;
            int k = k0 + kc * 8;
            int slice = k >> 5, within = k & 31;
            int g = r0 + row; if (g >= M) g = M - 1;
            short8_t v = *(const short8_t*)(A + (size_t)slice * SLICE_ELEMS + (size_t)g * 32 + within);
            int off = (row * 128 + kc * 16) ^ ((row & 7) << 4);
            *(short8_t*)(AsB + off) = v;
        }
#pragma unroll
        for (int i = 0; i < 8; ++i) {
            int c = tid + i * 256;
            int n = c >> 3, kc = c & 7;
            short8_t v = *(const short8_t*)(Wt + n * DIM + k0 + kc * 8);
            int off = (n * 128 + kc * 16) ^ ((n & 7) << 4);
            *(short8_t*)(BsB + off) = v;
        }
        __syncthreads();

#pragma unroll
        for (int kf = 0; kf < 2; ++kf) {
            int kb = kf * 64 + (l >> 4) * 16;
            short8_t a[4], b[4];
#pragma unroll
            for (int fm = 0; fm < 4; ++fm) {
                int ra = fm * 16 + (l & 15);
                a[fm] = *(const short8_t*)(AsB + ((ra * 128 + kb) ^ ((ra & 7) << 4)));
            }
#pragma unroll
            for (int fn = 0; fn < 4; ++fn) {
                int nb = w * 64 + fn * 16 + (l & 15);
                b[fn] = *(const short8_t*)(BsB + ((nb * 128 + kb) ^ ((nb & 7) << 4)));
            }
#pragma unroll
            for (int fm = 0; fm < 4; ++fm)
#pragma unroll
                for (int fn = 0; fn < 4; ++fn)
                    acc[fm][fn] = __builtin_amdgcn_mfma_f32_16x16x32_bf16(
                        a[fm], b[fn], acc[fm][fn], 0, 0, 0);
        }
        __syncthreads();
    }

    // C/D layout: col = l&15, row = (l>>4)*4 + i ; write SLICED
#pragma unroll
    for (int fm = 0; fm < 4; ++fm) {
#pragma unroll
        for (int i = 0; i < 4; ++i) {
            int row = r0 + fm * 16 + ((l >> 4) << 2) + i;
            if (row >= M) continue;
#pragma unroll
            for (int fn = 0; fn < 4; ++fn) {
                int col = w * 64 + fn * 16 + (l & 15);
                int slice = col >> 5;
                H[(size_t)slice * SLICE_ELEMS + (size_t)row * 32 + (col & 31)] = f2b(acc[fm][fn][i]);
            }
        }
    }
}

// ---------------- sliced aggregation, MLP-optimized ----------------
// 16-lane group per node. Per 16-edge round: one coalesced pair load (lane i ->
// pair i), then 16 shfl-broadcasts + 16 INDEPENDENT gathers back-to-back.
// Tail lanes: norm=0, src=0 -> gather row 0 * 0 (branch-free inner loop).

__global__ __launch_bounds__(256) void k_agg_sliced(const unsigned short* __restrict__ H,
                                                    const int* __restrict__ rowstart,
                                                    const int2* __restrict__ csr_pair,
                                                    const float* __restrict__ bias,
                                                    unsigned short* __restrict__ X,
                                                    float* __restrict__ gsum,
                                                    int write_out) {
    int slice = blockIdx.x & 7;
    int chunk = blockIdx.x >> 3;
    int g = threadIdx.x >> 4;        // 16 groups
    int lane = threadIdx.x & 15;
    const unsigned short* Hs = H + (size_t)slice * SLICE_ELEMS;
    unsigned short* Xs = X + (size_t)slice * SLICE_ELEMS;
    int d0 = slice * 32 + lane * 2;
    float b0 = bias[d0], b1 = bias[d0 + 1];
    float c0 = 0.f, c1 = 0.f;
    int nEnd = (chunk + 1) * NPC; if (nEnd > N_NODES) nEnd = N_NODES;
    for (int n = chunk * NPC + g; n < nEnd; n += 16) {
        int beg = rowstart[n], end = rowstart[n + 1];
        float a0 = 0.f, a1 = 0.f;
        for (int e0 = beg; e0 < end; e0 += 16) {
            int ee = e0 + lane;
            int px = 0, py = 0;
            if (ee < end) { int2 pp = csr_pair[ee]; px = pp.x; py = pp.y; }
#pragma unroll
            for (int i = 0; i < 16; ++i) {
                int sx = __shfl(px, i, 16);
                float nm = __int_as_float(__shfl(py, i, 16));
                ushort2_t v = *(const ushort2_t*)(Hs + (size_t)sx * 32 + (lane << 1));
                a0 = fmaf(nm, b2f(v.x), a0);
                a1 = fmaf(nm, b2f(v.y), a1);
            }
        }
        float o0 = fmaxf(a0 + b0, 0.f);
        float o1 = fmaxf(a1 + b1, 0.f);
        if (write_out) {
            ushort2_t o; o.x = f2b(o0); o.y = f2b(o1);
            *(ushort2_t*)(Xs + (size_t)n * 32 + (lane << 1)) = o;
        }
        c0 += o0; c1 += o1;
    }
    if (gsum) {
        __shared__ float sm0[256], sm1[256];
        int tid = threadIdx.x;
        sm0[tid] = c0; sm1[tid] = c1;
        __syncthreads();
#pragma unroll
        for (int off = 8; off >= 1; off >>= 1) {
            if (g < off) {
                sm0[tid] += sm0[tid + off * 16];
                sm1[tid] += sm1[tid + off * 16];
            }
            __syncthreads();
        }
        if (g == 0) {
            atomicAdd(&gsum[d0], sm0[lane]);
            atomicAdd(&gsum[d0 + 1], sm1[lane]);
        }
    }
}

// ---------------- FC head (single block, fp32) ----------------

__global__ __launch_bounds__(256) void k_fc(const float* __restrict__ gsum,
                                            const float* __restrict__ fcW1,
                                            const float* __restrict__ fcb1,
                                            const float* __restrict__ fcW2,
                                            const float* __restrict__ fcb2,
                                            const float* __restrict__ fcW3,
                                            const float* __restrict__ fcb3,
                                            float* __restrict__ out) {
    __shared__ float g[DIM];
    __shared__ float h[DIM];
    int t = threadIdx.x;
    g[t] = fmaxf(gsum[t] * (1.0f / (float)N_NODES), 0.f);
    __syncthreads();
    float acc = fcb1[t];
    for (int k = 0; k < DIM; ++k) acc = fmaf(g[k], fcW1[k * DIM + t], acc);
    h[t] = fmaxf(acc, 0.f);
    __syncthreads();
    acc = fcb2[t];
    for (int k = 0; k < DIM; ++k) acc = fmaf(h[k], fcW2[k * DIM + t], acc);
    __syncthreads();
    g[t] = fmaxf(acc, 0.f);
    __syncthreads();
    if (t < ACT) {
        float o = fcb3[t];
        for (int k = 0; k < DIM; ++k) o = fmaf(g[k], fcW3[k * ACT + t], o);
        out[t] = o;
    }
}

// ---------------- launch ----------------

extern "C" void kernel_launch(void* const* d_in, const int* in_sizes, int n_in,
                              void* d_out, int out_size, void* d_ws, size_t ws_size,
                              hipStream_t stream) {
    const float* x    = (const float*)d_in[0];
    const int*   ei   = (const int*)d_in[1];
    const float* W1   = (const float*)d_in[2];
    const float* b1   = (const float*)d_in[3];
    const float* W2   = (const float*)d_in[4];
    const float* b2   = (const float*)d_in[5];
    const float* fcW1 = (const float*)d_in[6];
    const float* fcb1 = (const float*)d_in[7];
    const float* fcW2 = (const float*)d_in[8];
    const float* fcb2 = (const float*)d_in[9];
    const float* fcW3 = (const float*)d_in[10];
    const float* fcb3 = (const float*)d_in[11];
    float* out = (float*)d_out;

    char* w = (char*)d_ws;
    size_t o = 0;
#define CARVE(name, type, count) \
    type* name = (type*)(w + o); \
    o += (((size_t)(count) * sizeof(type)) + 255) & ~(size_t)255;
    CARVE(degi, int, N_NODES)
    CARVE(rowstart, int, N_NODES + 1)
    CARVE(fillpos, int, N_NODES)
    CARVE(dinv, float, N_NODES)
    CARVE(lexc, int, N_NODES)
    CARVE(btot, int, SCAN_NB)
    CARVE(bbase, int, SCAN_NB)
    CARVE(csr_pair, int2, N_NODES + N_EDGES)
    CARVE(gsum, float, DIM)
    CARVE(xb,  unsigned short, (size_t)N_NODES * DIM)   // x bf16 sliced
    CARVE(W1t, unsigned short, DIM * DIM)
    CARVE(W2t, unsigned short, DIM * DIM)
    CARVE(Hbuf, unsigned short, (size_t)N_NODES * DIM)  // bf16 sliced
    CARVE(Xbuf, unsigned short, (size_t)N_NODES * DIM)  // bf16 sliced
#undef CARVE

    hipMemsetAsync(gsum, 0, DIM * sizeof(float), stream);
    hipMemsetAsync(degi, 0, N_NODES * sizeof(int), stream);

    // dtype prep
    k_cvt_x<<<(N_NODES * DIM / 8 + 255) / 256, 256, 0, stream>>>(x, xb);
    k_cvt_wt2<<<512, 256, 0, stream>>>(W1, W2, W1t, W2t);

    // CSR build
    k_deg_count<<<(N_EDGES + 255) / 256, 256, 0, stream>>>(ei, degi);
    k_scan_local<<<SCAN_NB, SCAN_B, 0, stream>>>(degi, lexc, btot);
    k_scan_tops<<<1, SCAN_B, 0, stream>>>(btot, bbase, rowstart);
    k_scan_apply<<<SCAN_NB, SCAN_B, 0, stream>>>(degi, lexc, bbase, rowstart, fillpos,
                                                 dinv, csr_pair);
    k_fill_edge<<<(N_EDGES + 255) / 256, 256, 0, stream>>>(ei, dinv, fillpos, csr_pair);

    // layer 1
    int gemm_grid = (N_NODES + 63) / 64;   // 782
    k_gemm_mfma<<<gemm_grid, 256, 0, stream>>>(xb, W1t, Hbuf, N_NODES);
    k_agg_sliced<<<8 * AGG_CHUNKS, 256, 0, stream>>>(Hbuf, rowstart, csr_pair, b1,
                                                     Xbuf, (float*)nullptr, 1);
    // layer 2 (agg fuses mean-pool column sum, no X write)
    k_gemm_mfma<<<gemm_grid, 256, 0, stream>>>(Xbuf, W2t, Hbuf, N_NODES);
    k_agg_sliced<<<8 * AGG_CHUNKS, 256, 0, stream>>>(Hbuf, rowstart, csr_pair, b2,
                                                     Xbuf, gsum, 0);

    // head
    k_fc<<<1, 256, 0, stream>>>(gsum, fcW1, fcb1, fcW2, fcb2, fcW3, fcb3, out);
}

// Round 6
// 294.507 us; speedup vs baseline: 2.4496x; 1.0961x over previous
//
#include <hip/hip_runtime.h>

#define N_NODES 50000
#define N_EDGES 800000
#define DIM 256
#define ACT 64
#define SCAN_B 256
#define SCAN_NB ((N_NODES + SCAN_B - 1) / SCAN_B)   // 196
#define SLICE_ELEMS ((size_t)N_NODES * 32)          // elems per 32-dim slice
#define AGG_CHUNKS 512
#define NPC ((N_NODES + AGG_CHUNKS - 1) / AGG_CHUNKS)  // 98 nodes per chunk

typedef __attribute__((ext_vector_type(8))) short short8_t;
typedef __attribute__((ext_vector_type(4))) float f32x4;
typedef __attribute__((ext_vector_type(4))) unsigned short ushort4_t;
typedef __attribute__((ext_vector_type(2))) unsigned short ushort2_t;

__device__ __forceinline__ unsigned short f2b(float x) {   // f32 -> bf16 RNE
    unsigned u = __float_as_uint(x);
    unsigned r = u + 0x7FFFu + ((u >> 16) & 1u);
    return (unsigned short)(r >> 16);
}
__device__ __forceinline__ float b2f(unsigned short u) {
    return __uint_as_float(((unsigned)u) << 16);
}

// ---------------- dtype conversion ----------------

// x fp32 row-major -> bf16 SLICED [slice][node][32]
__global__ __launch_bounds__(256) void k_cvt_x(const float* __restrict__ x,
                                               unsigned short* __restrict__ xb) {
    int i = blockIdx.x * blockDim.x + threadIdx.x;   // one thread = 8 elems
    const int TOT = N_NODES * DIM / 8;
    if (i >= TOT) return;
    const float4* src = (const float4*)(x) + (size_t)i * 2;
    float4 a = src[0], b = src[1];
    int row = i >> 5;
    int col0 = (i << 3) & 255;
    int slice = col0 >> 5, within = col0 & 31;
    ushort4_t lo, hi;
    lo.x = f2b(a.x); lo.y = f2b(a.y); lo.z = f2b(a.z); lo.w = f2b(a.w);
    hi.x = f2b(b.x); hi.y = f2b(b.y); hi.z = f2b(b.z); hi.w = f2b(b.w);
    ushort4_t* dst = (ushort4_t*)(xb + (size_t)slice * SLICE_ELEMS + (size_t)row * 32 + within);
    dst[0] = lo; dst[1] = hi;
}

// transpose + convert both W1,W2 [k][n] fp32 -> Wt [n][k] bf16
__global__ __launch_bounds__(256) void k_cvt_wt2(const float* __restrict__ W1,
                                                 const float* __restrict__ W2,
                                                 unsigned short* __restrict__ W1t,
                                                 unsigned short* __restrict__ W2t) {
    int b = blockIdx.x;
    const float* W = (b < 256) ? W1 : W2;
    unsigned short* Wt = (b < 256) ? W1t : W2t;
    int i = (b & 255) * 256 + threadIdx.x;
    int k = i >> 8, n = i & 255;
    Wt[n * DIM + k] = f2b(W[k * DIM + n]);
}

// ---------------- degree (degi pre-zeroed; self-loop accounted as +1 in scan) ----------------

__global__ void k_deg_count(const int* __restrict__ ei, int* degi) {
    int e = blockIdx.x * blockDim.x + threadIdx.x;
    if (e < N_EDGES) atomicAdd(&degi[ei[N_EDGES + e]], 1);  // dst row
}

// ---------------- hierarchical exclusive scan ----------------

__global__ __launch_bounds__(SCAN_B) void k_scan_local(const int* __restrict__ degi,
                                                       int* lexc, int* btot) {
    __shared__ int sm[SCAN_B];
    int t = threadIdx.x;
    int i = blockIdx.x * SCAN_B + t;
    int v = (i < N_NODES) ? (degi[i] + 1) : 0;   // +1 = self-loop
    sm[t] = v;
    __syncthreads();
#pragma unroll
    for (int off = 1; off < SCAN_B; off <<= 1) {
        int u = (t >= off) ? sm[t - off] : 0;
        __syncthreads();
        sm[t] += u;
        __syncthreads();
    }
    if (i < N_NODES) lexc[i] = sm[t] - v;
    if (t == SCAN_B - 1) btot[blockIdx.x] = sm[t];
}

__global__ __launch_bounds__(SCAN_B) void k_scan_tops(const int* __restrict__ btot,
                                                      int* bbase, int* rowstart) {
    __shared__ int sm[SCAN_B];
    int t = threadIdx.x;
    int v = (t < SCAN_NB) ? btot[t] : 0;
    sm[t] = v;
    __syncthreads();
#pragma unroll
    for (int off = 1; off < SCAN_B; off <<= 1) {
        int u = (t >= off) ? sm[t - off] : 0;
        __syncthreads();
        sm[t] += u;
        __syncthreads();
    }
    if (t < SCAN_NB) bbase[t] = sm[t] - v;
    if (t == SCAN_NB - 1) rowstart[N_NODES] = sm[t];
}

__global__ __launch_bounds__(SCAN_B) void k_scan_apply(const int* __restrict__ degi,
                                                       const int* __restrict__ lexc,
                                                       const int* __restrict__ bbase,
                                                       int* rowstart, int* fillpos,
                                                       float* dinv, int2* csr_pair) {
    int i = blockIdx.x * SCAN_B + threadIdx.x;
    if (i >= N_NODES) return;
    int rs = bbase[blockIdx.x] + lexc[i];
    rowstart[i] = rs;
    int d = degi[i] + 1;
    float di = rsqrtf((float)d);
    dinv[i] = di;
    int2 p; p.x = i; p.y = __float_as_int(di * di);
    csr_pair[rs] = p;          // self-loop entry first in row
    fillpos[i] = rs + 1;
}

__global__ void k_fill_edge(const int* __restrict__ ei,
                            const float* __restrict__ dinv, int* fillpos,
                            int2* csr_pair) {
    int e = blockIdx.x * blockDim.x + threadIdx.x;
    if (e < N_EDGES) {
        int s = ei[e];
        int d = ei[N_EDGES + e];
        int p = atomicAdd(&fillpos[d], 1);
        int2 pr; pr.x = s; pr.y = __float_as_int(dinv[s] * dinv[d]);
        csr_pair[p] = pr;
    }
}

// ---------------- bf16 MFMA GEMM: H = A @ Wt^T  (A, H in SLICED layout) ----------------

__global__ __launch_bounds__(256) void k_gemm_mfma(const unsigned short* __restrict__ A,
                                                   const unsigned short* __restrict__ Wt,
                                                   unsigned short* __restrict__ H,
                                                   int M) {
    __shared__ char lds[40960];          // As 64x64 bf16 (8KB) + Bs 256x64 bf16 (32KB)
    char* AsB = lds;
    char* BsB = lds + 8192;

    int tid = threadIdx.x;
    int w = tid >> 6;
    int l = tid & 63;
    int r0 = blockIdx.x * 64;

    f32x4 acc[4][4];
#pragma unroll
    for (int i = 0; i < 4; ++i)
#pragma unroll
        for (int j = 0; j < 4; ++j) acc[i][j] = (f32x4)(0.f);

    for (int kt = 0; kt < 4; ++kt) {
        int k0 = kt * 64;
#pragma unroll
        for (int i = 0; i < 2; ++i) {
            int c = tid + i * 256;
            int row = c >> 3, kc = c & 7;
            int k = k0 + kc * 8;
            int slice = k >> 5, within = k & 31;
            int g = r0 + row; if (g >= M) g = M - 1;
            short8_t v = *(const short8_t*)(A + (size_t)slice * SLICE_ELEMS + (size_t)g * 32 + within);
            int off = (row * 128 + kc * 16) ^ ((row & 7) << 4);
            *(short8_t*)(AsB + off) = v;
        }
#pragma unroll
        for (int i = 0; i < 8; ++i) {
            int c = tid + i * 256;
            int n = c >> 3, kc = c & 7;
            short8_t v = *(const short8_t*)(Wt + n * DIM + k0 + kc * 8);
            int off = (n * 128 + kc * 16) ^ ((n & 7) << 4);
            *(short8_t*)(BsB + off) = v;
        }
        __syncthreads();

#pragma unroll
        for (int kf = 0; kf < 2; ++kf) {
            int kb = kf * 64 + (l >> 4) * 16;
            short8_t a[4], b[4];
#pragma unroll
            for (int fm = 0; fm < 4; ++fm) {
                int ra = fm * 16 + (l & 15);
                a[fm] = *(const short8_t*)(AsB + ((ra * 128 + kb) ^ ((ra & 7) << 4)));
            }
#pragma unroll
            for (int fn = 0; fn < 4; ++fn) {
                int nb = w * 64 + fn * 16 + (l & 15);
                b[fn] = *(const short8_t*)(BsB + ((nb * 128 + kb) ^ ((nb & 7) << 4)));
            }
#pragma unroll
            for (int fm = 0; fm < 4; ++fm)
#pragma unroll
                for (int fn = 0; fn < 4; ++fn)
                    acc[fm][fn] = __builtin_amdgcn_mfma_f32_16x16x32_bf16(
                        a[fm], b[fn], acc[fm][fn], 0, 0, 0);
        }
        __syncthreads();
    }

    // C/D layout: col = l&15, row = (l>>4)*4 + i ; write SLICED
#pragma unroll
    for (int fm = 0; fm < 4; ++fm) {
#pragma unroll
        for (int i = 0; i < 4; ++i) {
            int row = r0 + fm * 16 + ((l >> 4) << 2) + i;
            if (row >= M) continue;
#pragma unroll
            for (int fn = 0; fn < 4; ++fn) {
                int col = w * 64 + fn * 16 + (l & 15);
                int slice = col >> 5;
                H[(size_t)slice * SLICE_ELEMS + (size_t)row * 32 + (col & 31)] = f2b(acc[fm][fn][i]);
            }
        }
    }
}

// ---------------- sliced aggregation: 8-lane group per node, 4 dims/lane ----------------
// Per 8-edge round: coalesced pair load (lane i -> pair i, pre-shifted src<<6),
// ds_write_b64 to group slot, then 8x { ds_read_b64 @imm offset -> 1 uint2
// gather -> 4 fma }. Wave = 8 groups -> ~1.5 wave-inst/edge. Tail lanes pad
// with (src=0, norm=0). Group is sub-wave: LDS is wave-synchronous, no barrier.

__global__ __launch_bounds__(256) void k_agg_sliced(const unsigned short* __restrict__ H,
                                                    const int* __restrict__ rowstart,
                                                    const int2* __restrict__ csr_pair,
                                                    const float* __restrict__ bias,
                                                    unsigned short* __restrict__ X,
                                                    float* __restrict__ gsum,
                                                    int write_out) {
    __shared__ long long pbuf[32 * 8];   // 32 groups x 8 pairs
    __shared__ float4 smr[256];
    int slice = blockIdx.x & 7;
    int chunk = blockIdx.x >> 3;
    int g = threadIdx.x >> 3;        // 32 groups of 8 lanes
    int lane = threadIdx.x & 7;
    const unsigned short* Hs = H + (size_t)slice * SLICE_ELEMS;
    const char* Hb = (const char*)Hs + (lane << 3);   // this lane's 4 dims (8B)
    unsigned short* Xs = X + (size_t)slice * SLICE_ELEMS;
    int d0 = slice * 32 + lane * 4;
    float4 bb = *(const float4*)&bias[d0];
    float c0 = 0.f, c1 = 0.f, c2 = 0.f, c3 = 0.f;
    long long* pslot = &pbuf[g << 3];
    int nEnd = (chunk + 1) * NPC; if (nEnd > N_NODES) nEnd = N_NODES;
    for (int n = chunk * NPC + g; n < nEnd; n += 32) {
        int beg = rowstart[n], end = rowstart[n + 1];
        float a0 = 0.f, a1 = 0.f, a2 = 0.f, a3 = 0.f;
        for (int e0 = beg; e0 < end; e0 += 8) {
            int ee = e0 + lane;
            int px6 = 0, py = 0;
            if (ee < end) { int2 pp = csr_pair[ee]; px6 = pp.x << 6; py = pp.y; }
            pslot[lane] = ((long long)(unsigned)py << 32) | (unsigned)px6;
#pragma unroll
            for (int i = 0; i < 8; ++i) {
                long long pv = pslot[i];
                int off = (int)(unsigned)pv;
                float nm = __int_as_float((int)(pv >> 32));
                uint2 u = *(const uint2*)(Hb + off);
                a0 = fmaf(nm, __uint_as_float(u.x << 16), a0);
                a1 = fmaf(nm, __uint_as_float(u.x & 0xFFFF0000u), a1);
                a2 = fmaf(nm, __uint_as_float(u.y << 16), a2);
                a3 = fmaf(nm, __uint_as_float(u.y & 0xFFFF0000u), a3);
            }
        }
        float o0 = fmaxf(a0 + bb.x, 0.f);
        float o1 = fmaxf(a1 + bb.y, 0.f);
        float o2 = fmaxf(a2 + bb.z, 0.f);
        float o3 = fmaxf(a3 + bb.w, 0.f);
        if (write_out) {
            ushort4_t o; o.x = f2b(o0); o.y = f2b(o1); o.z = f2b(o2); o.w = f2b(o3);
            *(ushort4_t*)(Xs + (size_t)n * 32 + (lane << 2)) = o;
        }
        c0 += o0; c1 += o1; c2 += o2; c3 += o3;
    }
    if (gsum) {
        int tid = threadIdx.x;
        smr[tid] = make_float4(c0, c1, c2, c3);
        __syncthreads();
#pragma unroll
        for (int off = 128; off >= 8; off >>= 1) {
            if (tid < off) {
                float4 a = smr[tid], b = smr[tid + off];
                smr[tid] = make_float4(a.x + b.x, a.y + b.y, a.z + b.z, a.w + b.w);
            }
            __syncthreads();
        }
        if (tid < 8) {   // tid == lane, d0 matches
            float4 v = smr[tid];
            atomicAdd(&gsum[d0], v.x);
            atomicAdd(&gsum[d0 + 1], v.y);
            atomicAdd(&gsum[d0 + 2], v.z);
            atomicAdd(&gsum[d0 + 3], v.w);
        }
    }
}

// ---------------- FC head (single block, fp32) ----------------

__global__ __launch_bounds__(256) void k_fc(const float* __restrict__ gsum,
                                            const float* __restrict__ fcW1,
                                            const float* __restrict__ fcb1,
                                            const float* __restrict__ fcW2,
                                            const float* __restrict__ fcb2,
                                            const float* __restrict__ fcW3,
                                            const float* __restrict__ fcb3,
                                            float* __restrict__ out) {
    __shared__ float g[DIM];
    __shared__ float h[DIM];
    int t = threadIdx.x;
    g[t] = fmaxf(gsum[t] * (1.0f / (float)N_NODES), 0.f);
    __syncthreads();
    float acc = fcb1[t];
    for (int k = 0; k < DIM; ++k) acc = fmaf(g[k], fcW1[k * DIM + t], acc);
    h[t] = fmaxf(acc, 0.f);
    __syncthreads();
    acc = fcb2[t];
    for (int k = 0; k < DIM; ++k) acc = fmaf(h[k], fcW2[k * DIM + t], acc);
    __syncthreads();
    g[t] = fmaxf(acc, 0.f);
    __syncthreads();
    if (t < ACT) {
        float o = fcb3[t];
        for (int k = 0; k < DIM; ++k) o = fmaf(g[k], fcW3[k * ACT + t], o);
        out[t] = o;
    }
}

// ---------------- launch ----------------

extern "C" void kernel_launch(void* const* d_in, const int* in_sizes, int n_in,
                              void* d_out, int out_size, void* d_ws, size_t ws_size,
                              hipStream_t stream) {
    const float* x    = (const float*)d_in[0];
    const int*   ei   = (const int*)d_in[1];
    const float* W1   = (const float*)d_in[2];
    const float* b1   = (const float*)d_in[3];
    const float* W2   = (const float*)d_in[4];
    const float* b2   = (const float*)d_in[5];
    const float* fcW1 = (const float*)d_in[6];
    const float* fcb1 = (const float*)d_in[7];
    const float* fcW2 = (const float*)d_in[8];
    const float* fcb2 = (const float*)d_in[9];
    const float* fcW3 = (const float*)d_in[10];
    const float* fcb3 = (const float*)d_in[11];
    float* out = (float*)d_out;

    char* w = (char*)d_ws;
    size_t o = 0;
#define CARVE(name, type, count) \
    type* name = (type*)(w + o); \
    o += (((size_t)(count) * sizeof(type)) + 255) & ~(size_t)255;
    CARVE(degi, int, N_NODES)
    CARVE(rowstart, int, N_NODES + 1)
    CARVE(fillpos, int, N_NODES)
    CARVE(dinv, float, N_NODES)
    CARVE(lexc, int, N_NODES)
    CARVE(btot, int, SCAN_NB)
    CARVE(bbase, int, SCAN_NB)
    CARVE(csr_pair, int2, N_NODES + N_EDGES)
    CARVE(gsum, float, DIM)
    CARVE(xb,  unsigned short, (size_t)N_NODES * DIM)   // x bf16 sliced
    CARVE(W1t, unsigned short, DIM * DIM)
    CARVE(W2t, unsigned short, DIM * DIM)
    CARVE(Hbuf, unsigned short, (size_t)N_NODES * DIM)  // bf16 sliced
    CARVE(Xbuf, unsigned short, (size_t)N_NODES * DIM)  // bf16 sliced
#undef CARVE

    hipMemsetAsync(gsum, 0, DIM * sizeof(float), stream);
    hipMemsetAsync(degi, 0, N_NODES * sizeof(int), stream);

    // dtype prep
    k_cvt_x<<<(N_NODES * DIM / 8 + 255) / 256, 256, 0, stream>>>(x, xb);
    k_cvt_wt2<<<512, 256, 0, stream>>>(W1, W2, W1t, W2t);

    // CSR build
    k_deg_count<<<(N_EDGES + 255) / 256, 256, 0, stream>>>(ei, degi);
    k_scan_local<<<SCAN_NB, SCAN_B, 0, stream>>>(degi, lexc, btot);
    k_scan_tops<<<1, SCAN_B, 0, stream>>>(btot, bbase, rowstart);
    k_scan_apply<<<SCAN_NB, SCAN_B, 0, stream>>>(degi, lexc, bbase, rowstart, fillpos,
                                                 dinv, csr_pair);
    k_fill_edge<<<(N_EDGES + 255) / 256, 256, 0, stream>>>(ei, dinv, fillpos, csr_pair);

    // layer 1
    int gemm_grid = (N_NODES + 63) / 64;   // 782
    k_gemm_mfma<<<gemm_grid, 256, 0, stream>>>(xb, W1t, Hbuf, N_NODES);
    k_agg_sliced<<<8 * AGG_CHUNKS, 256, 0, stream>>>(Hbuf, rowstart, csr_pair, b1,
                                                     Xbuf, (float*)nullptr, 1);
    // layer 2 (agg fuses mean-pool column sum, no X write)
    k_gemm_mfma<<<gemm_grid, 256, 0, stream>>>(Xbuf, W2t, Hbuf, N_NODES);
    k_agg_sliced<<<8 * AGG_CHUNKS, 256, 0, stream>>>(Hbuf, rowstart, csr_pair, b2,
                                                     Xbuf, gsum, 0);

    // head
    k_fc<<<1, 256, 0, stream>>>(gsum, fcW1, fcb1, fcW2, fcb2, fcW3, fcb3, out);
}